// Round 1
// 1135.640 us; speedup vs baseline: 1.8576x; 1.8576x over previous
//
#include <hip/hip_runtime.h>

#define FILL_F (-1.7014118346046923e38f)

// ---- order-preserving float <-> uint key (max in uint order == max in float order)
__device__ __forceinline__ unsigned xkey(float f) {
    unsigned u = __float_as_uint(f);
    return (u & 0x80000000u) ? ~u : (u | 0x80000000u);
}
__device__ __forceinline__ float xinv(unsigned k) {
    unsigned u = (k & 0x80000000u) ? (k ^ 0x80000000u) : ~k;
    return __uint_as_float(u);
}

#define PID_BITS 21
#define PID_MASK 0x1FFFFFu
#define MAX_R 1024

// old sorted path constants
#define SLOTS_OLD 2048
#define SHIFT_OLD 11
// new permuted path constants
#define SLOTS_NEW 256
#define SHIFT_NEW 8

// ================= fallback path (round-1 kernel) =================
__global__ __launch_bounds__(256) void init_fill_kernel(float* __restrict__ out, int n) {
    int i = blockIdx.x * blockDim.x + threadIdx.x;
    int p = i * 4;
    if (p + 3 < n) {
        float4 v; v.x = FILL_F; v.y = FILL_F; v.z = FILL_F; v.w = FILL_F;
        *reinterpret_cast<float4*>(out + p) = v;
    } else {
        for (int k = p; k < n; ++k) out[k] = FILL_F;
    }
}
__device__ __forceinline__ void atomic_max_float(float* addr, float v) {
    if (v >= 0.0f) atomicMax(reinterpret_cast<int*>(addr), __float_as_int(v));
    else           atomicMin(reinterpret_cast<unsigned*>(addr), __float_as_uint(v));
}
__global__ __launch_bounds__(256) void seg_max_fallback(const float* __restrict__ inten,
                                                        const int* __restrict__ pidx,
                                                        float* __restrict__ out,
                                                        int n_in, int n_out, int bc) {
    int t = blockIdx.x * blockDim.x + threadIdx.x;
    int p0 = t * 4;
    if (p0 >= n_in) return;
    const int4 idx = *reinterpret_cast<const int4*>(pidx + p0);
    for (int c = 0; c < bc; ++c) {
        const float4 v = *reinterpret_cast<const float4*>(inten + (size_t)c * n_in + p0);
        float* obase = out + (size_t)c * n_out;
        atomic_max_float(obase + idx.x, v.x);
        atomic_max_float(obase + idx.y, v.y);
        atomic_max_float(obase + idx.z, v.z);
        atomic_max_float(obase + idx.w, v.w);
    }
}

// ================= shared partition kernels =================
__global__ void zero_kernel(unsigned* a, int n) {
    int i = blockIdx.x * blockDim.x + threadIdx.x;
    if (i < n) a[i] = 0;
}

// per-block LDS histogram of bucket ids (bucket = slot >> shift)
__global__ __launch_bounds__(256) void hist_kernel(const int* __restrict__ pidx, int n_in,
                                                   unsigned* __restrict__ hist, int R, int shift) {
    __shared__ unsigned lh[MAX_R];
    int tid = threadIdx.x;
    for (int i = tid; i < R; i += 256) lh[i] = 0;
    __syncthreads();
    int q = blockIdx.x * 1024 + tid;            // int4 index; block covers 4096 particles
    #pragma unroll
    for (int it = 0; it < 4; ++it) {
        int qi = q + it * 256;
        if (qi * 4 < n_in) {
            int4 s = reinterpret_cast<const int4*>(pidx)[qi];
            atomicAdd(&lh[s.x >> shift], 1u);
            atomicAdd(&lh[s.y >> shift], 1u);
            atomicAdd(&lh[s.z >> shift], 1u);
            atomicAdd(&lh[s.w >> shift], 1u);
        }
    }
    __syncthreads();
    for (int i = tid; i < R; i += 256) if (lh[i]) atomicAdd(&hist[i], lh[i]);
}

// one-block parallel exclusive scan (R <= 1024) + init cursors
__global__ __launch_bounds__(1024) void scan_kernel(const unsigned* __restrict__ hist,
                                                    unsigned* __restrict__ base,
                                                    unsigned* __restrict__ cursor, int R) {
    __shared__ unsigned buf[2][1024];
    int t = threadIdx.x;
    unsigned v = (t < R) ? hist[t] : 0u;
    buf[0][t] = v;
    __syncthreads();
    int src = 0;
    for (int d = 1; d < 1024; d <<= 1) {
        unsigned x = buf[src][t];
        if (t >= d) x += buf[src][t - d];
        buf[src ^ 1][t] = x;
        src ^= 1;
        __syncthreads();
    }
    unsigned inc = buf[src][t];               // inclusive scan
    if (t < R) { unsigned ex = inc - v; base[t] = ex; cursor[t] = ex; }
    if (t == R - 1) base[R] = inc;
}

// ================= old sorted path (tier 2) =================
// scatter packed entries (slot_off << 21 | pid) into bucket lists
__global__ __launch_bounds__(256) void scatter_old_kernel(const int* __restrict__ pidx, int n_in,
                                                          unsigned* __restrict__ cursor,
                                                          unsigned* __restrict__ ids, int R, int shift) {
    __shared__ unsigned lcount[MAX_R], lbase[MAX_R], lcur[MAX_R];
    int tid = threadIdx.x;
    for (int i = tid; i < R; i += 256) { lcount[i] = 0; lcur[i] = 0; }
    __syncthreads();
    int q = blockIdx.x * 1024 + tid;
    int4 s[4];
    #pragma unroll
    for (int it = 0; it < 4; ++it) {
        int qi = q + it * 256;
        if (qi * 4 < n_in) {
            s[it] = reinterpret_cast<const int4*>(pidx)[qi];
            atomicAdd(&lcount[s[it].x >> shift], 1u);
            atomicAdd(&lcount[s[it].y >> shift], 1u);
            atomicAdd(&lcount[s[it].z >> shift], 1u);
            atomicAdd(&lcount[s[it].w >> shift], 1u);
        }
    }
    __syncthreads();
    for (int i = tid; i < R; i += 256) lbase[i] = atomicAdd(&cursor[i], lcount[i]);
    __syncthreads();
    const unsigned smask = (1u << shift) - 1u;
    #pragma unroll
    for (int it = 0; it < 4; ++it) {
        int qi = q + it * 256;
        if (qi * 4 < n_in) {
            int p0 = qi * 4;
            int sv[4] = { s[it].x, s[it].y, s[it].z, s[it].w };
            #pragma unroll
            for (int k = 0; k < 4; ++k) {
                int slot = sv[k];
                int b = slot >> shift;
                unsigned off = atomicAdd(&lcur[b], 1u);
                unsigned pack = ((unsigned)(slot & smask) << PID_BITS) | (unsigned)(p0 + k);
                ids[lbase[b] + off] = pack;
            }
        }
    }
}

// one block per (bucket, channel): LDS-accumulate 2048 slots, gather values
__global__ __launch_bounds__(256) void pool_old_kernel(const float* __restrict__ inten,
                                                       const unsigned* __restrict__ base,
                                                       const unsigned* __restrict__ hist,
                                                       const unsigned* __restrict__ ids,
                                                       float* __restrict__ out,
                                                       int n_in, int n_out) {
    __shared__ unsigned acc[SLOTS_OLD];
    const int b = blockIdx.x;
    const int c = blockIdx.y;
    const int tid = threadIdx.x;
    const unsigned fillk = xkey(FILL_F);
    #pragma unroll
    for (int j = tid; j < SLOTS_OLD; j += 256) acc[j] = fillk;
    __syncthreads();

    const unsigned beg = base[b];
    const unsigned cnt = hist[b];
    const float* __restrict__ row = inten + (size_t)c * n_in;
    const unsigned* __restrict__ lst = ids + beg;

    unsigned i = tid;
    for (; i + 768 < cnt; i += 1024) {   // 4-way MLP
        unsigned e0 = lst[i], e1 = lst[i + 256], e2 = lst[i + 512], e3 = lst[i + 768];
        float v0 = row[e0 & PID_MASK];
        float v1 = row[e1 & PID_MASK];
        float v2 = row[e2 & PID_MASK];
        float v3 = row[e3 & PID_MASK];
        atomicMax(&acc[e0 >> PID_BITS], xkey(v0));
        atomicMax(&acc[e1 >> PID_BITS], xkey(v1));
        atomicMax(&acc[e2 >> PID_BITS], xkey(v2));
        atomicMax(&acc[e3 >> PID_BITS], xkey(v3));
    }
    for (; i < cnt; i += 256) {
        unsigned e = lst[i];
        atomicMax(&acc[e >> PID_BITS], xkey(row[e & PID_MASK]));
    }
    __syncthreads();

    float* __restrict__ orow = out + (size_t)c * n_out + (size_t)b * SLOTS_OLD;
    #pragma unroll
    for (int j = tid; j < SLOTS_OLD; j += 256) orow[j] = xinv(acc[j]);
}

// ================= new permuted path (tier 1) =================
// scatter: dest[p] = bucket-sorted position (coalesced uint4 writes),
//          slots[pos] = slot offset within bucket (u16)
__global__ __launch_bounds__(256) void scatter_new_kernel(const int* __restrict__ pidx, int n_in,
                                                          unsigned* __restrict__ cursor,
                                                          unsigned* __restrict__ dest,
                                                          unsigned short* __restrict__ slots,
                                                          int R, int shift) {
    __shared__ unsigned lcount[MAX_R], lbase[MAX_R], lcur[MAX_R];
    const int tid = threadIdx.x;
    for (int i = tid; i < R; i += 256) { lcount[i] = 0; lcur[i] = 0; }
    __syncthreads();
    const int q = blockIdx.x * 1024 + tid;
    int4 s[4];
    #pragma unroll
    for (int it = 0; it < 4; ++it) {
        int qi = q + it * 256;
        if (qi * 4 < n_in) {
            s[it] = reinterpret_cast<const int4*>(pidx)[qi];
            atomicAdd(&lcount[s[it].x >> shift], 1u);
            atomicAdd(&lcount[s[it].y >> shift], 1u);
            atomicAdd(&lcount[s[it].z >> shift], 1u);
            atomicAdd(&lcount[s[it].w >> shift], 1u);
        }
    }
    __syncthreads();
    for (int i = tid; i < R; i += 256) lbase[i] = atomicAdd(&cursor[i], lcount[i]);
    __syncthreads();
    const unsigned smask = (1u << shift) - 1u;
    #pragma unroll
    for (int it = 0; it < 4; ++it) {
        int qi = q + it * 256;
        if (qi * 4 < n_in) {
            int p0 = qi * 4;
            int sv[4] = { s[it].x, s[it].y, s[it].z, s[it].w };
            unsigned pos[4];
            #pragma unroll
            for (int k = 0; k < 4; ++k) {
                int slot = sv[k];
                int bb = slot >> shift;
                unsigned off = atomicAdd(&lcur[bb], 1u);
                unsigned pp = lbase[bb] + off;
                pos[k] = pp;
                slots[pp] = (unsigned short)(slot & smask);
            }
            *reinterpret_cast<uint4*>(dest + p0) = make_uint4(pos[0], pos[1], pos[2], pos[3]);
        }
    }
}

// transpose+permute 16 channels: thread owns one particle, reads 16 coalesced
// channel rows into VGPRs, writes one 64B vector to plane[dest[p]*16].
__global__ __launch_bounds__(256) void tperm_kernel(const float* __restrict__ inten,
                                                    const unsigned* __restrict__ dest,
                                                    float* __restrict__ plane,
                                                    int n_in, int c0) {
    const int p = blockIdx.x * 256 + threadIdx.x;
    float v[16];
    #pragma unroll
    for (int c = 0; c < 16; ++c)
        v[c] = inten[(size_t)(c0 + c) * n_in + p];
    const unsigned d = dest[p];
    float4* dst = reinterpret_cast<float4*>(plane + (size_t)d * 16);
    dst[0] = make_float4(v[0],  v[1],  v[2],  v[3]);
    dst[1] = make_float4(v[4],  v[5],  v[6],  v[7]);
    dst[2] = make_float4(v[8],  v[9],  v[10], v[11]);
    dst[3] = make_float4(v[12], v[13], v[14], v[15]);
}

__device__ __forceinline__ void pool_entry16(unsigned* acc, unsigned s,
                                             float4 a, float4 b, float4 c, float4 d) {
    atomicMax(&acc[ 0 * SLOTS_NEW + s], xkey(a.x));
    atomicMax(&acc[ 1 * SLOTS_NEW + s], xkey(a.y));
    atomicMax(&acc[ 2 * SLOTS_NEW + s], xkey(a.z));
    atomicMax(&acc[ 3 * SLOTS_NEW + s], xkey(a.w));
    atomicMax(&acc[ 4 * SLOTS_NEW + s], xkey(b.x));
    atomicMax(&acc[ 5 * SLOTS_NEW + s], xkey(b.y));
    atomicMax(&acc[ 6 * SLOTS_NEW + s], xkey(b.z));
    atomicMax(&acc[ 7 * SLOTS_NEW + s], xkey(b.w));
    atomicMax(&acc[ 8 * SLOTS_NEW + s], xkey(c.x));
    atomicMax(&acc[ 9 * SLOTS_NEW + s], xkey(c.y));
    atomicMax(&acc[10 * SLOTS_NEW + s], xkey(c.z));
    atomicMax(&acc[11 * SLOTS_NEW + s], xkey(c.w));
    atomicMax(&acc[12 * SLOTS_NEW + s], xkey(d.x));
    atomicMax(&acc[13 * SLOTS_NEW + s], xkey(d.y));
    atomicMax(&acc[14 * SLOTS_NEW + s], xkey(d.z));
    atomicMax(&acc[15 * SLOTS_NEW + s], xkey(d.w));
}

// one block per bucket: stream cnt*64B sequential values + u16 slots,
// LDS accumulate [16ch][256slots], write 16 coalesced rows.
__global__ __launch_bounds__(256) void pool16_kernel(const float4* __restrict__ plane,
                                                     const unsigned short* __restrict__ slots,
                                                     const unsigned* __restrict__ base,
                                                     const unsigned* __restrict__ hist,
                                                     float* __restrict__ out,
                                                     int n_out, int c0) {
    __shared__ unsigned acc[16 * SLOTS_NEW];
    const int b = blockIdx.x;
    const int tid = threadIdx.x;
    const unsigned fillk = xkey(FILL_F);
    #pragma unroll
    for (int j = tid; j < 16 * SLOTS_NEW; j += 256) acc[j] = fillk;
    __syncthreads();

    const unsigned beg = base[b];
    const unsigned cnt = hist[b];
    const unsigned short* __restrict__ sl = slots + beg;
    const float4* __restrict__ pv = plane + (size_t)beg * 4;

    unsigned i = tid;
    for (; i + 768 < cnt; i += 1024) {   // 4-way MLP, sequential 64B streams
        unsigned s0 = sl[i], s1 = sl[i + 256], s2 = sl[i + 512], s3 = sl[i + 768];
        size_t q0 = (size_t)i * 4, q1 = (size_t)(i + 256) * 4,
               q2 = (size_t)(i + 512) * 4, q3 = (size_t)(i + 768) * 4;
        float4 a0 = pv[q0 + 0], a1 = pv[q0 + 1], a2 = pv[q0 + 2], a3 = pv[q0 + 3];
        float4 b0 = pv[q1 + 0], b1 = pv[q1 + 1], b2 = pv[q1 + 2], b3 = pv[q1 + 3];
        float4 e0 = pv[q2 + 0], e1 = pv[q2 + 1], e2 = pv[q2 + 2], e3 = pv[q2 + 3];
        float4 f0 = pv[q3 + 0], f1 = pv[q3 + 1], f2 = pv[q3 + 2], f3 = pv[q3 + 3];
        pool_entry16(acc, s0, a0, a1, a2, a3);
        pool_entry16(acc, s1, b0, b1, b2, b3);
        pool_entry16(acc, s2, e0, e1, e2, e3);
        pool_entry16(acc, s3, f0, f1, f2, f3);
    }
    for (; i < cnt; i += 256) {
        unsigned s0 = sl[i];
        size_t q0 = (size_t)i * 4;
        float4 a0 = pv[q0 + 0], a1 = pv[q0 + 1], a2 = pv[q0 + 2], a3 = pv[q0 + 3];
        pool_entry16(acc, s0, a0, a1, a2, a3);
    }
    __syncthreads();

    #pragma unroll
    for (int c = 0; c < 16; ++c) {
        // 256 threads, 256 slots: one coalesced store per channel
        out[(size_t)(c0 + c) * n_out + (size_t)b * SLOTS_NEW + tid] = xinv(acc[c * SLOTS_NEW + tid]);
    }
}

extern "C" void kernel_launch(void* const* d_in, const int* in_sizes, int n_in_arrs,
                              void* d_out, int out_size, void* d_ws, size_t ws_size,
                              hipStream_t stream) {
    const float* inten = (const float*)d_in[0];   // [B, C, N_in] fp32
    const int* pidx    = (const int*)d_in[1];     // [N_in] int32
    float* out         = (float*)d_out;           // [B, C, N_out] fp32

    const int total_in = in_sizes[0];
    const int n_in     = in_sizes[1];
    const int bc       = total_in / n_in;
    const int n_out    = out_size / bc;
    const int threads  = 256;

    auto al = [](size_t x) { return (x + 255) & ~(size_t)255; };
    const size_t off_hist   = 0;
    const size_t off_base   = al(off_hist + (size_t)MAX_R * 4);
    const size_t off_cursor = al(off_base + (size_t)(MAX_R + 1) * 4);
    const size_t off_dest   = al(off_cursor + (size_t)MAX_R * 4);   // also 'ids' for old path
    const size_t off_slots  = al(off_dest + (size_t)n_in * 4);
    const size_t off_plane  = al(off_slots + (size_t)n_in * 2);
    const size_t need_new   = off_plane + (size_t)n_in * 16 * 4;    // plane reused per group
    const size_t need_old   = off_dest + (size_t)n_in * 4;

    const bool base_ok = (n_in <= (1 << PID_BITS)) && (n_in % 4096 == 0);
    const int R_new = n_out / SLOTS_NEW;
    const int R_old = n_out / SLOTS_OLD;
    const bool new_ok = base_ok && (n_out % SLOTS_NEW == 0) && (R_new >= 1) && (R_new <= MAX_R) &&
                        (bc % 16 == 0) && (n_in % 256 == 0) && (ws_size >= need_new);
    const bool old_ok = base_ok && (n_out % SLOTS_OLD == 0) && (R_old >= 1) && (R_old <= MAX_R) &&
                        (ws_size >= need_old);

    unsigned* hist   = (unsigned*)((char*)d_ws + off_hist);
    unsigned* basep  = (unsigned*)((char*)d_ws + off_base);
    unsigned* cursor = (unsigned*)((char*)d_ws + off_cursor);

    if (new_ok) {
        unsigned* dest        = (unsigned*)((char*)d_ws + off_dest);
        unsigned short* slots = (unsigned short*)((char*)d_ws + off_slots);
        float* plane          = (float*)((char*)d_ws + off_plane);

        zero_kernel<<<(R_new + 255) / 256, 256, 0, stream>>>(hist, R_new);
        const int pblocks = n_in / 4096;
        hist_kernel<<<pblocks, threads, 0, stream>>>(pidx, n_in, hist, R_new, SHIFT_NEW);
        scan_kernel<<<1, 1024, 0, stream>>>(hist, basep, cursor, R_new);
        scatter_new_kernel<<<pblocks, threads, 0, stream>>>(pidx, n_in, cursor, dest, slots,
                                                            R_new, SHIFT_NEW);
        for (int g = 0; g < bc; g += 16) {
            tperm_kernel<<<n_in / 256, threads, 0, stream>>>(inten, dest, plane, n_in, g);
            pool16_kernel<<<R_new, threads, 0, stream>>>((const float4*)plane, slots, basep, hist,
                                                         out, n_out, g);
        }
        return;
    }

    if (old_ok) {
        unsigned* ids = (unsigned*)((char*)d_ws + off_dest);
        zero_kernel<<<(R_old + 255) / 256, 256, 0, stream>>>(hist, R_old);
        const int pblocks = n_in / 4096;
        hist_kernel<<<pblocks, threads, 0, stream>>>(pidx, n_in, hist, R_old, SHIFT_OLD);
        scan_kernel<<<1, 1024, 0, stream>>>(hist, basep, cursor, R_old);
        scatter_old_kernel<<<pblocks, threads, 0, stream>>>(pidx, n_in, cursor, ids, R_old, SHIFT_OLD);
        dim3 grid(R_old, bc);
        pool_old_kernel<<<grid, threads, 0, stream>>>(inten, basep, hist, ids, out, n_in, n_out);
        return;
    }

    // ---- atomic fallback ----
    int init_quads = (out_size + 3) / 4;
    init_fill_kernel<<<(init_quads + threads - 1) / threads, threads, 0, stream>>>(out, out_size);
    int quads = (n_in + 3) / 4;
    seg_max_fallback<<<(quads + threads - 1) / threads, threads, 0, stream>>>(
        inten, pidx, out, n_in, n_out, bc);
}